// Round 1
// baseline (678.998 us; speedup 1.0000x reference)
//
#include <hip/hip_runtime.h>
#include <cstddef>

// ButterFlyNet2D IDFT forward, f32 baseline.
// Activation layout between layers: A[gy][gx][i][k][l][b][p][q]
//   -> per block (gy,gx) a contiguous Y[256][Nb] matrix, Nb = 64*S2*S2,
//      m = i*4 + k*2 + l, n = b*S2*S2 + p*S2 + q.
// Per-block weights w[gy][gx][oc][i][k][l] are contiguous [256][256] row-major.

// ---------------- Layer 0 ----------------
// y[b,o,p,q] = relu( b0[o] + sum_{i,k,l} xs[b,i,2p+k,2q+l] * w0[o,i,k,l] )
// o = gy*128 + gx*64 + c ; write into A1[gy][gx][c][p&1][q&1][b][p>>1][q>>1]
__global__ __launch_bounds__(256)
void layer0_kernel(const float* __restrict__ xr, const float* __restrict__ xi,
                   const float* __restrict__ w0, const float* __restrict__ b0,
                   float* __restrict__ A1) {
    const int o = blockIdx.y;                      // 0..255
    const int n = blockIdx.x * 256 + threadIdx.x;  // 0..65535 = (b,p,q)
    const int b = n >> 10;
    const int p = (n >> 5) & 31;
    const int q = n & 31;
    const float* wrow = w0 + o * 16;
    float acc = b0[o];
#pragma unroll
    for (int k = 0; k < 2; ++k) {
#pragma unroll
        for (int l = 0; l < 2; ++l) {
            const int idx = b * 4096 + (2 * p + k) * 64 + (2 * q + l);
            const float vr = xr[idx], vi = xi[idx];
            acc = fmaf(fmaxf(vr, 0.f),  wrow[0  + k * 2 + l], acc);
            acc = fmaf(fmaxf(vi, 0.f),  wrow[4  + k * 2 + l], acc);
            acc = fmaf(fmaxf(-vr, 0.f), wrow[8  + k * 2 + l], acc);
            acc = fmaf(fmaxf(-vi, 0.f), wrow[12 + k * 2 + l], acc);
        }
    }
    acc = fmaxf(acc, 0.f);
    const int gy = o >> 7, gx = (o >> 6) & 1, c = o & 63;
    const int kp = p & 1, lp = q & 1, pp = p >> 1, qp = q >> 1;
    const size_t flat = (size_t)((((gy * 2 + gx) * 64 + c) * 2 + kp) * 2 + lp) * (64 * 256)
                      + (size_t)(b * 256 + pp * 16 + qp);
    A1[flat] = acc;
}

// ---------------- Recursion layers 1..5 ----------------
// Per block (gy,gx): Z[256][Nb] = W[256][256] * Y[256][Nb], relu(+bias),
// scatter to child blocks in A_{lyr+1}.
// grid: x = S2*S2 (n tiles of 64), y = 4 (oc tiles of 64), z = G*G (blocks)
__global__ __launch_bounds__(256)
void rec_kernel(const float* __restrict__ Ain, const float* __restrict__ W,
                const float* __restrict__ bias, float* __restrict__ Aout,
                const int lgG, const int lgS2, const int isLast) {
    __shared__ float Wt[64][36];   // [oc_local][kk], padded stride 36 (16B-aligned rows)
    __shared__ float Yt[32][64];   // [kk][n_local]

    const int G  = 1 << lgG;
    const int S2 = 1 << lgS2;
    const int Nb = 64 << (2 * lgS2);

    const int bid = blockIdx.z;
    const int ot  = blockIdx.y;
    const int nt  = blockIdx.x;

    const float* Wblk = W   + (size_t)bid * 65536 + (size_t)ot * 64 * 256;
    const float* Yblk = Ain + (size_t)bid * 256 * (size_t)Nb + (size_t)nt * 64;

    const int tid = threadIdx.x;
    const int ty = tid >> 4;   // 0..15 (oc groups of 4)
    const int tx = tid & 15;   // 0..15 (n groups of 4)

    const int w_oc = tid >> 2;          // 0..63
    const int w_k8 = (tid & 3) * 8;     // 0,8,16,24
    const int y_kk = tid >> 3;          // 0..31
    const int y_n8 = (tid & 7) * 8;     // 0..56

    float acc[4][4] = {};

    for (int k0 = 0; k0 < 256; k0 += 32) {
        const float4 wv0 = *(const float4*)(Wblk + w_oc * 256 + k0 + w_k8);
        const float4 wv1 = *(const float4*)(Wblk + w_oc * 256 + k0 + w_k8 + 4);
        const float4 yv0 = *(const float4*)(Yblk + (size_t)(k0 + y_kk) * Nb + y_n8);
        const float4 yv1 = *(const float4*)(Yblk + (size_t)(k0 + y_kk) * Nb + y_n8 + 4);
        __syncthreads();   // previous iteration's LDS reads complete
        *(float4*)(&Wt[w_oc][w_k8])     = wv0;
        *(float4*)(&Wt[w_oc][w_k8 + 4]) = wv1;
        *(float4*)(&Yt[y_kk][y_n8])     = yv0;
        *(float4*)(&Yt[y_kk][y_n8 + 4]) = yv1;
        __syncthreads();
#pragma unroll
        for (int kk = 0; kk < 32; ++kk) {
            const float a0 = Wt[ty * 4 + 0][kk];
            const float a1 = Wt[ty * 4 + 1][kk];
            const float a2 = Wt[ty * 4 + 2][kk];
            const float a3 = Wt[ty * 4 + 3][kk];
            const float4 bv = *(const float4*)(&Yt[kk][tx * 4]);
            acc[0][0] = fmaf(a0, bv.x, acc[0][0]);
            acc[0][1] = fmaf(a0, bv.y, acc[0][1]);
            acc[0][2] = fmaf(a0, bv.z, acc[0][2]);
            acc[0][3] = fmaf(a0, bv.w, acc[0][3]);
            acc[1][0] = fmaf(a1, bv.x, acc[1][0]);
            acc[1][1] = fmaf(a1, bv.y, acc[1][1]);
            acc[1][2] = fmaf(a1, bv.z, acc[1][2]);
            acc[1][3] = fmaf(a1, bv.w, acc[1][3]);
            acc[2][0] = fmaf(a2, bv.x, acc[2][0]);
            acc[2][1] = fmaf(a2, bv.y, acc[2][1]);
            acc[2][2] = fmaf(a2, bv.z, acc[2][2]);
            acc[2][3] = fmaf(a2, bv.w, acc[2][3]);
            acc[3][0] = fmaf(a3, bv.x, acc[3][0]);
            acc[3][1] = fmaf(a3, bv.y, acc[3][1]);
            acc[3][2] = fmaf(a3, bv.z, acc[3][2]);
            acc[3][3] = fmaf(a3, bv.w, acc[3][3]);
        }
    }

    const int gy = bid >> lgG, gx = bid & (G - 1);
    const int NS2 = S2 >> 1;
#pragma unroll
    for (int ii = 0; ii < 4; ++ii) {
        const int oc = ot * 64 + ty * 4 + ii;
        const float bi = bias[(size_t)bid * 256 + oc];
        const int yl = oc >> 7, xl = (oc >> 6) & 1, c = oc & 63;
        const int cy = 2 * gy + yl, cx = 2 * gx + xl;
        const size_t base = (size_t)((cy * (2 * G) + cx) * 64 + c);
#pragma unroll
        for (int jj = 0; jj < 4; ++jj) {
            const float v = fmaxf(acc[ii][jj] + bi, 0.f);
            const int n = nt * 64 + tx * 4 + jj;
            size_t flat;
            if (isLast) {
                // A6[cy][cx][c][b], n == b
                flat = base * 64 + (size_t)n;
            } else {
                const int b   = n >> (2 * lgS2);
                const int rem = n & ((1 << (2 * lgS2)) - 1);
                const int p = rem >> lgS2, q = rem & (S2 - 1);
                flat = ((base * 2 + (p & 1)) * 2 + (q & 1)) * (size_t)(64 * NS2 * NS2)
                     + (size_t)(b * NS2 * NS2 + (p >> 1) * NS2 + (q >> 1));
            }
            Aout[flat] = v;
        }
    }
}

// ---------------- Final layer ----------------
// out[b, cy, cx] = (relu(bf0 + sum_i A6[cy][cx][i][b]*wf[cy,cx,0,i])
//                 - relu(bf2 + sum_i A6[cy][cx][i][b]*wf[cy,cx,2,i])) / 4096
__global__ __launch_bounds__(64)
void final_kernel(const float* __restrict__ A6, const float* __restrict__ wf,
                  const float* __restrict__ bf, float* __restrict__ out) {
    const int blk = blockIdx.x;      // cy*64 + cx
    const int b = threadIdx.x;       // 0..63
    const float* Y   = A6 + (size_t)blk * 4096;
    const float* w0r = wf + (size_t)blk * 256;         // o = 0
    const float* w2r = wf + (size_t)blk * 256 + 128;   // o = 2
    float a0 = 0.f, a2 = 0.f;
#pragma unroll 8
    for (int i = 0; i < 64; ++i) {
        const float y = Y[i * 64 + b];
        a0 = fmaf(y, w0r[i], a0);
        a2 = fmaf(y, w2r[i], a2);
    }
    a0 = fmaxf(a0 + bf[blk * 4 + 0], 0.f);
    a2 = fmaxf(a2 + bf[blk * 4 + 2], 0.f);
    const int cy = blk >> 6, cx = blk & 63;
    out[(size_t)b * 4096 + cy * 64 + cx] = (a0 - a2) * (1.0f / 4096.0f);
}

extern "C" void kernel_launch(void* const* d_in, const int* in_sizes, int n_in,
                              void* d_out, int out_size, void* d_ws, size_t ws_size,
                              hipStream_t stream) {
    (void)in_sizes; (void)n_in; (void)out_size; (void)ws_size;

    const float* xr = (const float*)d_in[0];
    const float* xi = (const float*)d_in[1];
    const float* w0 = (const float*)d_in[2];
    const float* b0 = (const float*)d_in[3];
    const float* wrec[5] = { (const float*)d_in[4],  (const float*)d_in[6],
                             (const float*)d_in[8],  (const float*)d_in[10],
                             (const float*)d_in[12] };
    const float* brec[5] = { (const float*)d_in[5],  (const float*)d_in[7],
                             (const float*)d_in[9],  (const float*)d_in[11],
                             (const float*)d_in[13] };
    const float* wf = (const float*)d_in[14];
    const float* bf = (const float*)d_in[15];
    float* out = (float*)d_out;

    // two 64 MiB ping-pong activation buffers (16M floats each)
    float* bufA = (float*)d_ws;
    float* bufB = bufA + (size_t)(16u << 20);

    layer0_kernel<<<dim3(256, 256), 256, 0, stream>>>(xr, xi, w0, b0, bufA);

    float* src = bufA;
    float* dst = bufB;
    for (int lyr = 1; lyr <= 5; ++lyr) {
        const int lgG = lyr;          // G = 2^lyr blocks per axis
        const int lgS2 = 5 - lyr;     // S2 = 2^(5-lyr) output spatial
        const int S2 = 1 << lgS2;
        const int G = 1 << lgG;
        dim3 grid(S2 * S2, 4, G * G);
        rec_kernel<<<grid, 256, 0, stream>>>(src, wrec[lyr - 1], brec[lyr - 1], dst,
                                             lgG, lgS2, (lyr == 5) ? 1 : 0);
        float* t = src; src = dst; dst = t;
    }
    // src now holds A6 = [cy][cx][c][b]
    final_kernel<<<4096, 64, 0, stream>>>(src, wf, bf, out);
}

// Round 2
// 361.983 us; speedup vs baseline: 1.8758x; 1.8758x over previous
//
#include <hip/hip_runtime.h>
#include <cstddef>

// ButterFlyNet2D IDFT forward. Recursion layers via split-bf16 MFMA (3-pass).
// Activation layout between layers: A[gy][gx][i][k][l][b][p][q]
//   -> per block a contiguous Y[256][Nb], Nb = 64*S2*S2.
// Per-block weights w[gy][gx][oc][i][k][l] contiguous [256][256] row-major.

typedef __attribute__((ext_vector_type(8))) short bf16x8;
typedef __attribute__((ext_vector_type(4))) float f32x4;

__device__ inline unsigned short bf16_rn(float x) {
    unsigned u = __builtin_bit_cast(unsigned, x);
    unsigned r = (u + 0x7FFFu + ((u >> 16) & 1u)) >> 16;
    return (unsigned short)r;
}
__device__ inline float bf16_to_f(unsigned short h) {
    unsigned u = ((unsigned)h) << 16;
    return __builtin_bit_cast(float, u);
}

// ---------------- Layer 0 (scalar, BW-bound) ----------------
__global__ __launch_bounds__(256)
void layer0_kernel(const float* __restrict__ xr, const float* __restrict__ xi,
                   const float* __restrict__ w0, const float* __restrict__ b0,
                   float* __restrict__ A1) {
    const int o = blockIdx.y;                      // 0..255
    const int n = blockIdx.x * 256 + threadIdx.x;  // (b,p,q)
    const int b = n >> 10;
    const int p = (n >> 5) & 31;
    const int q = n & 31;
    const float* wrow = w0 + o * 16;
    float acc = b0[o];
#pragma unroll
    for (int k = 0; k < 2; ++k) {
#pragma unroll
        for (int l = 0; l < 2; ++l) {
            const int idx = b * 4096 + (2 * p + k) * 64 + (2 * q + l);
            const float vr = xr[idx], vi = xi[idx];
            acc = fmaf(fmaxf(vr, 0.f),  wrow[0  + k * 2 + l], acc);
            acc = fmaf(fmaxf(vi, 0.f),  wrow[4  + k * 2 + l], acc);
            acc = fmaf(fmaxf(-vr, 0.f), wrow[8  + k * 2 + l], acc);
            acc = fmaf(fmaxf(-vi, 0.f), wrow[12 + k * 2 + l], acc);
        }
    }
    acc = fmaxf(acc, 0.f);
    const int gy = o >> 7, gx = (o >> 6) & 1, c = o & 63;
    const int kp = p & 1, lp = q & 1, pp = p >> 1, qp = q >> 1;
    const size_t flat = (size_t)((((gy * 2 + gx) * 64 + c) * 2 + kp) * 2 + lp) * (64 * 256)
                      + (size_t)(b * 256 + pp * 16 + qp);
    A1[flat] = acc;
}

// ---------------- Recursion layers 1..5 : split-bf16 MFMA ----------------
// Workgroup: 256 threads = 4 waves; computes C[256][NT] for one (block, ntile).
// Wave w owns output rows [64w, 64w+64). 3 passes: Whi*Yhi + Whi*Ylo + Wlo*Yhi.
template<int NT>
__global__ __launch_bounds__(256, 2)
void rec_mfma_kernel(const float* __restrict__ Ain, const float* __restrict__ W,
                     const float* __restrict__ bias, float* __restrict__ Aout,
                     const int lgG, const int lgS2, const int isLast) {
    constexpr int NF   = NT / 16;   // n fragments per wave (all waves share cols)
    constexpr int KSEG = NT / 8;    // k-elems per thread for Y staging
    constexpr int LD   = 40;        // LDS row stride (bf16 elems), pad vs 32

    __shared__ unsigned short Whi[256 * LD];
    __shared__ unsigned short Wlo[256 * LD];
    __shared__ unsigned short Yhi[NT * LD];
    __shared__ unsigned short Ylo[NT * LD];

    const int G  = 1 << lgG;
    const int S2 = 1 << lgS2;
    const int Nb = 64 << (2 * lgS2);

    const int bid = blockIdx.z;
    const int nt  = blockIdx.x;

    const float* Wblk = W   + (size_t)bid * 65536;
    const float* Yblk = Ain + (size_t)bid * 256 * (size_t)Nb + (size_t)nt * NT;

    const int tid  = threadIdx.x;
    const int wave = tid >> 6;
    const int lane = tid & 63;
    const int l16  = lane & 15;
    const int lk   = lane >> 4;           // 0..3 (k-group of 8)

    // Y staging ownership: column yc, k-segment yh
    const int yc = tid & (NT - 1);
    const int yh = tid >> (NT == 128 ? 7 : 6);

    f32x4 acc[4][NF];
#pragma unroll
    for (int m = 0; m < 4; ++m)
#pragma unroll
        for (int n = 0; n < NF; ++n)
            acc[m][n] = (f32x4){0.f, 0.f, 0.f, 0.f};

    for (int k0 = 0; k0 < 256; k0 += 32) {
        // ---- global loads (f32) ----
        float4 wv[8];
        const float* wr = Wblk + (size_t)tid * 256 + k0;
#pragma unroll
        for (int s = 0; s < 8; ++s) wv[s] = *(const float4*)(wr + 4 * s);
        float yv[KSEG];
#pragma unroll
        for (int j = 0; j < KSEG; ++j)
            yv[j] = Yblk[(size_t)(k0 + yh * KSEG + j) * Nb + yc];

        __syncthreads();   // previous compute phase's LDS reads complete

        // ---- convert to hi/lo bf16, stage to LDS ----
#pragma unroll
        for (int s = 0; s < 4; ++s) {
            union { bf16x8 v; unsigned short u[8]; } H, L;
            const float* f = (const float*)&wv[2 * s];
#pragma unroll
            for (int e = 0; e < 8; ++e) {
                const unsigned short h = bf16_rn(f[e]);
                H.u[e] = h;
                L.u[e] = bf16_rn(f[e] - bf16_to_f(h));
            }
            *(bf16x8*)&Whi[tid * LD + 8 * s] = H.v;
            *(bf16x8*)&Wlo[tid * LD + 8 * s] = L.v;
        }
#pragma unroll
        for (int s = 0; s < KSEG / 8; ++s) {
            union { bf16x8 v; unsigned short u[8]; } H, L;
#pragma unroll
            for (int e = 0; e < 8; ++e) {
                const float x = yv[8 * s + e];
                const unsigned short h = bf16_rn(x);
                H.u[e] = h;
                L.u[e] = bf16_rn(x - bf16_to_f(h));
            }
            *(bf16x8*)&Yhi[yc * LD + yh * KSEG + 8 * s] = H.v;
            *(bf16x8*)&Ylo[yc * LD + yh * KSEG + 8 * s] = L.v;
        }
        __syncthreads();

        // ---- MFMA phase ----
        bf16x8 ahi[4], alo[4];
#pragma unroll
        for (int m = 0; m < 4; ++m) {
            const int row = wave * 64 + m * 16 + l16;
            ahi[m] = *(const bf16x8*)&Whi[row * LD + 8 * lk];
            alo[m] = *(const bf16x8*)&Wlo[row * LD + 8 * lk];
        }
#pragma unroll
        for (int n = 0; n < NF; ++n) {
            const int col = n * 16 + l16;
            const bf16x8 bhi = *(const bf16x8*)&Yhi[col * LD + 8 * lk];
            const bf16x8 blo = *(const bf16x8*)&Ylo[col * LD + 8 * lk];
#pragma unroll
            for (int m = 0; m < 4; ++m) {
                acc[m][n] = __builtin_amdgcn_mfma_f32_16x16x32_bf16(ahi[m], bhi, acc[m][n], 0, 0, 0);
                acc[m][n] = __builtin_amdgcn_mfma_f32_16x16x32_bf16(ahi[m], blo, acc[m][n], 0, 0, 0);
                acc[m][n] = __builtin_amdgcn_mfma_f32_16x16x32_bf16(alo[m], bhi, acc[m][n], 0, 0, 0);
            }
        }
    }

    // ---- epilogue: bias + relu + scatter to child blocks ----
    const int gy = bid >> lgG, gx = bid & (G - 1);
    const int NS2 = S2 >> 1;
#pragma unroll
    for (int m = 0; m < 4; ++m) {
#pragma unroll
        for (int r = 0; r < 4; ++r) {
            const int oc = wave * 64 + m * 16 + lk * 4 + r;   // C/D: row=(lane>>4)*4+reg
            const float bi = bias[bid * 256 + oc];
            const int yl = oc >> 7, xl = (oc >> 6) & 1, c = oc & 63;
            const int cy = 2 * gy + yl, cx = 2 * gx + xl;
            const size_t base = (size_t)((cy * (2 * G) + cx) * 64 + c);
#pragma unroll
            for (int n = 0; n < NF; ++n) {
                const float v = fmaxf(acc[m][n][r] + bi, 0.f);
                const int ng = nt * NT + n * 16 + l16;        // C/D: col=lane&15
                size_t flat;
                if (isLast) {
                    flat = base * 64 + (size_t)ng;            // A6[cy][cx][c][b]
                } else {
                    const int b   = ng >> (2 * lgS2);
                    const int rem = ng & ((1 << (2 * lgS2)) - 1);
                    const int p = rem >> lgS2, q = rem & (S2 - 1);
                    flat = ((base * 2 + (p & 1)) * 2 + (q & 1)) * (size_t)(64 * NS2 * NS2)
                         + (size_t)(b * NS2 * NS2 + (p >> 1) * NS2 + (q >> 1));
                }
                Aout[flat] = v;
            }
        }
    }
}

// ---------------- Final layer (scalar, BW-bound) ----------------
__global__ __launch_bounds__(64)
void final_kernel(const float* __restrict__ A6, const float* __restrict__ wf,
                  const float* __restrict__ bf, float* __restrict__ out) {
    const int blk = blockIdx.x;      // cy*64 + cx
    const int b = threadIdx.x;       // 0..63
    const float* Y   = A6 + (size_t)blk * 4096;
    const float* w0r = wf + (size_t)blk * 256;         // o = 0
    const float* w2r = wf + (size_t)blk * 256 + 128;   // o = 2
    float a0 = 0.f, a2 = 0.f;
#pragma unroll 8
    for (int i = 0; i < 64; ++i) {
        const float y = Y[i * 64 + b];
        a0 = fmaf(y, w0r[i], a0);
        a2 = fmaf(y, w2r[i], a2);
    }
    a0 = fmaxf(a0 + bf[blk * 4 + 0], 0.f);
    a2 = fmaxf(a2 + bf[blk * 4 + 2], 0.f);
    const int cy = blk >> 6, cx = blk & 63;
    out[(size_t)b * 4096 + cy * 64 + cx] = (a0 - a2) * (1.0f / 4096.0f);
}

extern "C" void kernel_launch(void* const* d_in, const int* in_sizes, int n_in,
                              void* d_out, int out_size, void* d_ws, size_t ws_size,
                              hipStream_t stream) {
    (void)in_sizes; (void)n_in; (void)out_size; (void)ws_size;

    const float* xr = (const float*)d_in[0];
    const float* xi = (const float*)d_in[1];
    const float* w0 = (const float*)d_in[2];
    const float* b0 = (const float*)d_in[3];
    const float* wrec[5] = { (const float*)d_in[4],  (const float*)d_in[6],
                             (const float*)d_in[8],  (const float*)d_in[10],
                             (const float*)d_in[12] };
    const float* brec[5] = { (const float*)d_in[5],  (const float*)d_in[7],
                             (const float*)d_in[9],  (const float*)d_in[11],
                             (const float*)d_in[13] };
    const float* wf = (const float*)d_in[14];
    const float* bf = (const float*)d_in[15];
    float* out = (float*)d_out;

    float* bufA = (float*)d_ws;
    float* bufB = bufA + (size_t)(16u << 20);

    layer0_kernel<<<dim3(256, 256), 256, 0, stream>>>(xr, xi, w0, b0, bufA);

    float* src = bufA;
    float* dst = bufB;
    for (int lyr = 1; lyr <= 5; ++lyr) {
        const int lgG = lyr;
        const int lgS2 = 5 - lyr;
        const int S2 = 1 << lgS2;
        const int G = 1 << lgG;
        const int Nb = 64 * S2 * S2;
        if (lyr < 5) {
            dim3 grid(Nb / 128, 1, G * G);
            rec_mfma_kernel<128><<<grid, 256, 0, stream>>>(src, wrec[lyr - 1], brec[lyr - 1], dst,
                                                           lgG, lgS2, 0);
        } else {
            dim3 grid(1, 1, G * G);
            rec_mfma_kernel<64><<<grid, 256, 0, stream>>>(src, wrec[lyr - 1], brec[lyr - 1], dst,
                                                          lgG, lgS2, 1);
        }
        float* t = src; src = dst; dst = t;
    }
    final_kernel<<<4096, 64, 0, stream>>>(src, wf, bf, out);
}